// Round 2
// baseline (335.204 us; speedup 1.0000x reference)
//
#include <hip/hip_runtime.h>
#include <hip/hip_bf16.h>

#define V_NODES 100000
#define DIM 128
#define BATCH 16384
#define SAMP 64
#define NEDGE 640000

// ---------- K1: count in-degrees (int atomics, 640K ops) ----------
__global__ void k_count(const int* __restrict__ dst, int* __restrict__ cnt, int E) {
    int e = blockIdx.x * blockDim.x + threadIdx.x;
    if (e < E) atomicAdd(&cnt[dst[e]], 1);
}

// ---------- K2a: per-1024-chunk sums ----------
__global__ void k_bsum(const int* __restrict__ cnt, int* __restrict__ bsum, int V) {
    __shared__ int red[4];
    int b = blockIdx.x, t = threadIdx.x;
    int s = 0;
    int base = b * 1024;
    for (int i = 0; i < 4; ++i) {
        int idx = base + i * 256 + t;
        if (idx < V) s += cnt[idx];
    }
    for (int m = 32; m >= 1; m >>= 1) s += __shfl_xor(s, m, 64);
    int lane = t & 63, wid = t >> 6;
    if (lane == 0) red[wid] = s;
    __syncthreads();
    if (t == 0) bsum[b] = red[0] + red[1] + red[2] + red[3];
}

// ---------- K2b: tiny serial scan of chunk sums ----------
__global__ void k_bscan(const int* __restrict__ bsum, int* __restrict__ boff, int nb) {
    if (threadIdx.x == 0 && blockIdx.x == 0) {
        int run = 0;
        for (int i = 0; i < nb; ++i) { boff[i] = run; run += bsum[i]; }
    }
}

// ---------- K2c: exclusive CSR offsets + dinv = 1/sqrt(deg+1) ----------
__global__ void k_offs(const int* __restrict__ cnt, const int* __restrict__ boff,
                       int* __restrict__ offs, float* __restrict__ dinv, int V) {
    __shared__ int wsum[4];
    int b = blockIdx.x, t = threadIdx.x;
    int lane = t & 63, wid = t >> 6;
    int base = b * 1024 + t * 4;
    int c[4];
    for (int j = 0; j < 4; ++j) {
        int idx = base + j;
        c[j] = (idx < V) ? cnt[idx] : 0;
    }
    int tot = c[0] + c[1] + c[2] + c[3];
    int x = tot;
    for (int off = 1; off < 64; off <<= 1) {
        int n = __shfl_up(x, off, 64);
        if (lane >= off) x += n;
    }
    int lex = x - tot;               // exclusive prefix within wave (of thread totals)
    if (lane == 63) wsum[wid] = x;   // wave total
    __syncthreads();
    int wpre = 0;
    for (int w = 0; w < wid; ++w) wpre += wsum[w];
    int o = boff[b] + wpre + lex;
    int pre = 0;
    for (int j = 0; j < 4; ++j) {
        int idx = base + j;
        if (idx < V) {
            offs[idx] = o + pre;
            dinv[idx] = 1.0f / sqrtf((float)(c[j] + 1));  // deg includes self-loop
        }
        pre += c[j];
    }
}

// ---------- K3: fill CSR (int atomic cursors) ----------
__global__ void k_fill(const int* __restrict__ src, const int* __restrict__ dst,
                       const int* __restrict__ offs, int* __restrict__ cursor,
                       int* __restrict__ csr, int E) {
    int e = blockIdx.x * blockDim.x + threadIdx.x;
    if (e < E) {
        int d = dst[e];
        int pos = atomicAdd(&cursor[d], 1);
        csr[offs[d] + pos] = src[e];
    }
}

// ---------- K4: aggregate in EMBEDDING space (linear commutes with agg) ----------
// one wave per node; lane holds 2 dims (float2)
__global__ __launch_bounds__(256) void k_agg(const float* __restrict__ emb,
                     const int* __restrict__ offs, const int* __restrict__ cnt,
                     const int* __restrict__ csr, const float* __restrict__ dinv,
                     float* __restrict__ out, int V) {
    int wid = threadIdx.x >> 6;
    int lane = threadIdx.x & 63;
    int v = blockIdx.x * 4 + wid;
    if (v >= V) return;
    float dv = dinv[v];
    float2 e0 = ((const float2*)(emb + (size_t)v * DIM))[lane];
    float wself = dv * dv;                 // self-loop norm
    float2 acc;
    acc.x = wself * e0.x; acc.y = wself * e0.y;
    int beg = offs[v], num = cnt[v];
    for (int i = 0; i < num; ++i) {
        int s = csr[beg + i];
        float w = dv * dinv[s];
        float2 e = ((const float2*)(emb + (size_t)s * DIM))[lane];
        acc.x += w * e.x; acc.y += w * e.y;
    }
    ((float2*)(out + (size_t)v * DIM))[lane] = acc;
}

// ---------- K5: in-place GEMM  nodes = nodes @ W + bias ----------
// 256 thr = 8 row-groups x 32 col-groups; each thread 4x4 register tile
__global__ __launch_bounds__(256) void k_gemm(float* __restrict__ nodes,
                      const float* __restrict__ W, const float* __restrict__ bias, int V) {
    __shared__ float rows[32][128];   // 16 KB
    __shared__ float wld[32][128];    // 16 KB
    int t = threadIdx.x;
    int rowbase = blockIdx.x * 32;
    {   // stage 32 rows (4096 floats) as float4
        const float4* g = (const float4*)(nodes + (size_t)rowbase * DIM);
        float4* s = (float4*)&rows[0][0];
        #pragma unroll
        for (int i = 0; i < 4; ++i) s[t + i * 256] = g[t + i * 256];
    }
    int tr = t >> 5, tc = t & 31;
    float acc[4][4] = {{0.f}};
    for (int kt = 0; kt < 4; ++kt) {
        __syncthreads();              // rows staged (kt=0) / wld reads done (kt>0)
        {   // stage W rows [kt*32, kt*32+32)
            const float4* g = (const float4*)(W + kt * 32 * DIM);
            float4* s = (float4*)&wld[0][0];
            #pragma unroll
            for (int i = 0; i < 4; ++i) s[t + i * 256] = g[t + i * 256];
        }
        __syncthreads();
        #pragma unroll
        for (int k = 0; k < 32; ++k) {
            float4 wv = *(const float4*)&wld[k][tc * 4];
            float a0 = rows[tr * 4 + 0][kt * 32 + k];
            float a1 = rows[tr * 4 + 1][kt * 32 + k];
            float a2 = rows[tr * 4 + 2][kt * 32 + k];
            float a3 = rows[tr * 4 + 3][kt * 32 + k];
            acc[0][0] += a0 * wv.x; acc[0][1] += a0 * wv.y; acc[0][2] += a0 * wv.z; acc[0][3] += a0 * wv.w;
            acc[1][0] += a1 * wv.x; acc[1][1] += a1 * wv.y; acc[1][2] += a1 * wv.z; acc[1][3] += a1 * wv.w;
            acc[2][0] += a2 * wv.x; acc[2][1] += a2 * wv.y; acc[2][2] += a2 * wv.z; acc[2][3] += a2 * wv.w;
            acc[3][0] += a3 * wv.x; acc[3][1] += a3 * wv.y; acc[3][2] += a3 * wv.z; acc[3][3] += a3 * wv.w;
        }
    }
    float4 bv = *(const float4*)&bias[tc * 4];
    #pragma unroll
    for (int i = 0; i < 4; ++i) {
        int r = rowbase + tr * 4 + i;
        if (r < V) {
            float4 o;
            o.x = acc[i][0] + bv.x; o.y = acc[i][1] + bv.y;
            o.z = acc[i][2] + bv.z; o.w = acc[i][3] + bv.w;
            *(float4*)(nodes + (size_t)r * DIM + tc * 4) = o;
        }
    }
}

// ---------- K6: scores[b,s] = dot(nodes[items[b]], nodes[samples[b,s]]) ----------
__global__ __launch_bounds__(256) void k_score(const float* __restrict__ nodes,
                      const int* __restrict__ items, const int* __restrict__ samples,
                      float* __restrict__ out) {
    int b = blockIdx.x;
    int lane = threadIdx.x & 63;
    int wid = threadIdx.x >> 6;
    int item = items[b];
    float2 iv = ((const float2*)(nodes + (size_t)item * DIM))[lane];
    for (int s = wid; s < SAMP; s += 4) {
        int j = samples[b * SAMP + s];
        float2 sv = ((const float2*)(nodes + (size_t)j * DIM))[lane];
        float p = iv.x * sv.x + iv.y * sv.y;
        for (int m = 32; m >= 1; m >>= 1) p += __shfl_xor(p, m, 64);
        if (lane == 0) out[b * SAMP + s] = p;
    }
}

extern "C" void kernel_launch(void* const* d_in, const int* in_sizes, int n_in,
                              void* d_out, int out_size, void* d_ws, size_t ws_size,
                              hipStream_t stream) {
    const int*   items   = (const int*)d_in[0];
    const int*   samples = (const int*)d_in[1];
    const int*   edges   = (const int*)d_in[2];
    const float* emb     = (const float*)d_in[3];
    const float* W       = (const float*)d_in[4];
    const float* bias    = (const float*)d_in[5];
    float* out = (float*)d_out;

    char* ws = (char*)d_ws;
    int*   cnt    = (int*)(ws + 0);                    // V ints
    int*   cursor = (int*)(ws + (512 << 10));          // V ints
    float* dinv   = (float*)(ws + (1 << 20));          // V floats
    int*   offs   = (int*)(ws + 3 * (512 << 10));      // V ints
    int*   bsum   = (int*)(ws + (2 << 20));            // ~98 ints
    int*   boff   = (int*)(ws + (2 << 20) + 4096);     // ~98 ints
    int*   csr    = (int*)(ws + (4 << 20));            // E ints
    float* nodes  = (float*)(ws + (8 << 20));          // V*DIM floats (agg, then in-place GEMM)

    const int* esrc = edges;
    const int* edst = edges + NEDGE;

    hipMemsetAsync(ws, 0, (1 << 20), stream);  // zero cnt + cursor

    int nb = (V_NODES + 1023) / 1024;
    k_count<<<(NEDGE + 255) / 256, 256, 0, stream>>>(edst, cnt, NEDGE);
    k_bsum <<<nb, 256, 0, stream>>>(cnt, bsum, V_NODES);
    k_bscan<<<1, 64, 0, stream>>>(bsum, boff, nb);
    k_offs <<<nb, 256, 0, stream>>>(cnt, boff, offs, dinv, V_NODES);
    k_fill <<<(NEDGE + 255) / 256, 256, 0, stream>>>(esrc, edst, offs, cursor, csr, NEDGE);
    k_agg  <<<(V_NODES + 3) / 4, 256, 0, stream>>>(emb, offs, cnt, csr, dinv, nodes, V_NODES);
    k_gemm <<<V_NODES / 32, 256, 0, stream>>>(nodes, W, bias, V_NODES);
    k_score<<<BATCH, 256, 0, stream>>>(nodes, items, samples, out);
}

// Round 3
// 326.209 us; speedup vs baseline: 1.0276x; 1.0276x over previous
//
#include <hip/hip_runtime.h>
#include <hip/hip_bf16.h>

#define V_NODES 100000
#define DIM 128
#define BATCH 16384
#define SAMP 64
#define NEDGE 640000

// ---------- K1: count in-degrees (int atomics, 640K ops) ----------
__global__ void k_count(const int* __restrict__ dst, int* __restrict__ cnt, int E) {
    int e = blockIdx.x * blockDim.x + threadIdx.x;
    if (e < E) atomicAdd(&cnt[dst[e]], 1);
}

// ---------- K2a: per-1024-chunk sums ----------
__global__ void k_bsum(const int* __restrict__ cnt, int* __restrict__ bsum, int V) {
    __shared__ int red[4];
    int b = blockIdx.x, t = threadIdx.x;
    int s = 0;
    int base = b * 1024;
    for (int i = 0; i < 4; ++i) {
        int idx = base + i * 256 + t;
        if (idx < V) s += cnt[idx];
    }
    for (int m = 32; m >= 1; m >>= 1) s += __shfl_xor(s, m, 64);
    int lane = t & 63, wid = t >> 6;
    if (lane == 0) red[wid] = s;
    __syncthreads();
    if (t == 0) bsum[b] = red[0] + red[1] + red[2] + red[3];
}

// ---------- K2b: tiny serial scan of chunk sums ----------
__global__ void k_bscan(const int* __restrict__ bsum, int* __restrict__ boff, int nb) {
    if (threadIdx.x == 0 && blockIdx.x == 0) {
        int run = 0;
        for (int i = 0; i < nb; ++i) { boff[i] = run; run += bsum[i]; }
    }
}

// ---------- K2c: exclusive CSR offsets + dinv = 1/sqrt(deg+1) ----------
__global__ void k_offs(const int* __restrict__ cnt, const int* __restrict__ boff,
                       int* __restrict__ offs, float* __restrict__ dinv, int V) {
    __shared__ int wsum[4];
    int b = blockIdx.x, t = threadIdx.x;
    int lane = t & 63, wid = t >> 6;
    int base = b * 1024 + t * 4;
    int c[4];
    for (int j = 0; j < 4; ++j) {
        int idx = base + j;
        c[j] = (idx < V) ? cnt[idx] : 0;
    }
    int tot = c[0] + c[1] + c[2] + c[3];
    int x = tot;
    for (int off = 1; off < 64; off <<= 1) {
        int n = __shfl_up(x, off, 64);
        if (lane >= off) x += n;
    }
    int lex = x - tot;               // exclusive prefix within wave (of thread totals)
    if (lane == 63) wsum[wid] = x;   // wave total
    __syncthreads();
    int wpre = 0;
    for (int w = 0; w < wid; ++w) wpre += wsum[w];
    int o = boff[b] + wpre + lex;
    int pre = 0;
    for (int j = 0; j < 4; ++j) {
        int idx = base + j;
        if (idx < V) {
            offs[idx] = o + pre;
            dinv[idx] = 1.0f / sqrtf((float)(c[j] + 1));  // deg includes self-loop
        }
        pre += c[j];
    }
}

// ---------- K3: fill CSR (int atomic cursors) ----------
__global__ void k_fill(const int* __restrict__ src, const int* __restrict__ dst,
                       const int* __restrict__ offs, int* __restrict__ cursor,
                       int* __restrict__ csr, int E) {
    int e = blockIdx.x * blockDim.x + threadIdx.x;
    if (e < E) {
        int d = dst[e];
        int pos = atomicAdd(&cursor[d], 1);
        csr[offs[d] + pos] = src[e];
    }
}

// ---------- K4: aggregate in EMBEDDING space (linear commutes with agg) ----------
// one wave per node; lane holds 2 dims (float2).
// Neighbor ids + dinv prefetched lane-parallel, broadcast via shuffle, so the
// emb gathers are independent across iterations (memory pipeline friendly).
__global__ __launch_bounds__(256) void k_agg(const float* __restrict__ emb,
                     const int* __restrict__ offs, const int* __restrict__ cnt,
                     const int* __restrict__ csr, const float* __restrict__ dinv,
                     float* __restrict__ out, int V) {
    int wid = threadIdx.x >> 6;
    int lane = threadIdx.x & 63;
    int v = blockIdx.x * 4 + wid;
    if (v >= V) return;
    float dv = dinv[v];
    int beg = offs[v], num = cnt[v];
    int nid = 0; float nw = 0.0f;
    if (lane < num) {                       // one coalesced id load + one dinv gather
        nid = csr[beg + lane];
        nw = dinv[nid];
    }
    float2 e0 = ((const float2*)(emb + (size_t)v * DIM))[lane];
    float wself = dv * dv;                 // self-loop norm
    float2 acc;
    acc.x = wself * e0.x; acc.y = wself * e0.y;
    int n0 = min(num, 64);
    for (int i = 0; i < n0; ++i) {
        int s = __shfl(nid, i, 64);
        float w = dv * __shfl(nw, i, 64);
        float2 e = ((const float2*)(emb + (size_t)s * DIM))[lane];
        acc.x += w * e.x; acc.y += w * e.y;
    }
    for (int i = 64; i < num; ++i) {        // cold fallback (deg>64 ~ impossible, Poisson(6.4))
        int s = csr[beg + i];
        float w = dv * dinv[s];
        float2 e = ((const float2*)(emb + (size_t)s * DIM))[lane];
        acc.x += w * e.x; acc.y += w * e.y;
    }
    ((float2*)(out + (size_t)v * DIM))[lane] = acc;
}

// ---------- K5: in-place GEMM  nodes = nodes @ W + bias ----------
// 256 thr = 8 row-groups x 32 col-groups; each thread 4x4 register tile
__global__ __launch_bounds__(256) void k_gemm(float* __restrict__ nodes,
                      const float* __restrict__ W, const float* __restrict__ bias, int V) {
    __shared__ float rows[32][128];   // 16 KB
    __shared__ float wld[32][128];    // 16 KB
    int t = threadIdx.x;
    int rowbase = blockIdx.x * 32;
    {   // stage 32 rows (4096 floats) as float4
        const float4* g = (const float4*)(nodes + (size_t)rowbase * DIM);
        float4* s = (float4*)&rows[0][0];
        #pragma unroll
        for (int i = 0; i < 4; ++i) s[t + i * 256] = g[t + i * 256];
    }
    int tr = t >> 5, tc = t & 31;
    float acc[4][4] = {{0.f}};
    for (int kt = 0; kt < 4; ++kt) {
        __syncthreads();              // rows staged (kt=0) / wld reads done (kt>0)
        {   // stage W rows [kt*32, kt*32+32)
            const float4* g = (const float4*)(W + kt * 32 * DIM);
            float4* s = (float4*)&wld[0][0];
            #pragma unroll
            for (int i = 0; i < 4; ++i) s[t + i * 256] = g[t + i * 256];
        }
        __syncthreads();
        #pragma unroll
        for (int k = 0; k < 32; ++k) {
            float4 wv = *(const float4*)&wld[k][tc * 4];
            float a0 = rows[tr * 4 + 0][kt * 32 + k];
            float a1 = rows[tr * 4 + 1][kt * 32 + k];
            float a2 = rows[tr * 4 + 2][kt * 32 + k];
            float a3 = rows[tr * 4 + 3][kt * 32 + k];
            acc[0][0] += a0 * wv.x; acc[0][1] += a0 * wv.y; acc[0][2] += a0 * wv.z; acc[0][3] += a0 * wv.w;
            acc[1][0] += a1 * wv.x; acc[1][1] += a1 * wv.y; acc[1][2] += a1 * wv.z; acc[1][3] += a1 * wv.w;
            acc[2][0] += a2 * wv.x; acc[2][1] += a2 * wv.y; acc[2][2] += a2 * wv.z; acc[2][3] += a2 * wv.w;
            acc[3][0] += a3 * wv.x; acc[3][1] += a3 * wv.y; acc[3][2] += a3 * wv.z; acc[3][3] += a3 * wv.w;
        }
    }
    float4 bv = *(const float4*)&bias[tc * 4];
    #pragma unroll
    for (int i = 0; i < 4; ++i) {
        int r = rowbase + tr * 4 + i;
        if (r < V) {
            float4 o;
            o.x = acc[i][0] + bv.x; o.y = acc[i][1] + bv.y;
            o.z = acc[i][2] + bv.z; o.w = acc[i][3] + bv.w;
            *(float4*)(nodes + (size_t)r * DIM + tc * 4) = o;
        }
    }
}

// ---------- K6: scores[b,s] = dot(nodes[items[b]], nodes[samples[b,s]]) ----------
// one block per item; 4 threads per sample (each owns 32 dims in registers);
// reduction depth = 2 shuffles within the 4-lane group.
__global__ __launch_bounds__(256) void k_score(const float* __restrict__ nodes,
                      const int* __restrict__ items, const int* __restrict__ samples,
                      float* __restrict__ out) {
    int b = blockIdx.x;
    int t = threadIdx.x;
    int q = t & 3;       // dim-chunk 0..3 (32 floats each)
    int sidx = t >> 2;   // sample 0..63
    int item = items[b];
    const float4* irow = (const float4*)(nodes + (size_t)item * DIM + q * 32);
    float4 iv[8];
    #pragma unroll
    for (int i = 0; i < 8; ++i) iv[i] = irow[i];   // broadcast across 4 q-groups, L1-hit

    int j = samples[b * SAMP + sidx];
    const float4* srow = (const float4*)(nodes + (size_t)j * DIM + q * 32);
    float4 sv[8];
    #pragma unroll
    for (int i = 0; i < 8; ++i) sv[i] = srow[i];   // 8 independent loads in flight

    float p0 = 0.f, p1 = 0.f, p2 = 0.f, p3 = 0.f;
    #pragma unroll
    for (int i = 0; i < 8; i += 4) {
        p0 += iv[i+0].x*sv[i+0].x + iv[i+0].y*sv[i+0].y + iv[i+0].z*sv[i+0].z + iv[i+0].w*sv[i+0].w;
        p1 += iv[i+1].x*sv[i+1].x + iv[i+1].y*sv[i+1].y + iv[i+1].z*sv[i+1].z + iv[i+1].w*sv[i+1].w;
        p2 += iv[i+2].x*sv[i+2].x + iv[i+2].y*sv[i+2].y + iv[i+2].z*sv[i+2].z + iv[i+2].w*sv[i+2].w;
        p3 += iv[i+3].x*sv[i+3].x + iv[i+3].y*sv[i+3].y + iv[i+3].z*sv[i+3].z + iv[i+3].w*sv[i+3].w;
    }
    float p = (p0 + p1) + (p2 + p3);
    p += __shfl_xor(p, 1, 64);
    p += __shfl_xor(p, 2, 64);
    if (q == 0) out[b * SAMP + sidx] = p;
}

extern "C" void kernel_launch(void* const* d_in, const int* in_sizes, int n_in,
                              void* d_out, int out_size, void* d_ws, size_t ws_size,
                              hipStream_t stream) {
    const int*   items   = (const int*)d_in[0];
    const int*   samples = (const int*)d_in[1];
    const int*   edges   = (const int*)d_in[2];
    const float* emb     = (const float*)d_in[3];
    const float* W       = (const float*)d_in[4];
    const float* bias    = (const float*)d_in[5];
    float* out = (float*)d_out;

    char* ws = (char*)d_ws;
    int*   cnt    = (int*)(ws + 0);                    // V ints
    int*   cursor = (int*)(ws + (512 << 10));          // V ints
    float* dinv   = (float*)(ws + (1 << 20));          // V floats
    int*   offs   = (int*)(ws + 3 * (512 << 10));      // V ints
    int*   bsum   = (int*)(ws + (2 << 20));            // ~98 ints
    int*   boff   = (int*)(ws + (2 << 20) + 4096);     // ~98 ints
    int*   csr    = (int*)(ws + (4 << 20));            // E ints
    float* nodes  = (float*)(ws + (8 << 20));          // V*DIM floats (agg, then in-place GEMM)

    const int* esrc = edges;
    const int* edst = edges + NEDGE;

    hipMemsetAsync(ws, 0, (1 << 20), stream);  // zero cnt + cursor

    int nb = (V_NODES + 1023) / 1024;
    k_count<<<(NEDGE + 255) / 256, 256, 0, stream>>>(edst, cnt, NEDGE);
    k_bsum <<<nb, 256, 0, stream>>>(cnt, bsum, V_NODES);
    k_bscan<<<1, 64, 0, stream>>>(bsum, boff, nb);
    k_offs <<<nb, 256, 0, stream>>>(cnt, boff, offs, dinv, V_NODES);
    k_fill <<<(NEDGE + 255) / 256, 256, 0, stream>>>(esrc, edst, offs, cursor, csr, NEDGE);
    k_agg  <<<(V_NODES + 3) / 4, 256, 0, stream>>>(emb, offs, cnt, csr, dinv, nodes, V_NODES);
    k_gemm <<<V_NODES / 32, 256, 0, stream>>>(nodes, W, bias, V_NODES);
    k_score<<<BATCH, 256, 0, stream>>>(nodes, items, samples, out);
}

// Round 4
// 278.765 us; speedup vs baseline: 1.2025x; 1.1702x over previous
//
#include <hip/hip_runtime.h>
#include <hip/hip_bf16.h>

#define V_NODES 100000
#define DIM 128
#define BATCH 16384
#define SAMP 64
#define NEDGE 640000

// bf16 helpers: raw-bit unpack (exact) and RNE pack
__device__ __forceinline__ float bl(unsigned u) { return __uint_as_float(u << 16); }
__device__ __forceinline__ float bh(unsigned u) { return __uint_as_float(u & 0xffff0000u); }
__device__ __forceinline__ unsigned short f2bf(float x) {
    unsigned u = __float_as_uint(x);
    return (unsigned short)((u + 0x7fffu + ((u >> 16) & 1u)) >> 16);
}

// ---------- K0: fp32 -> bf16 table conversion (emb_h) ----------
__global__ void k_cvt(const float* __restrict__ in, unsigned short* __restrict__ outh, int n4) {
    int i = blockIdx.x * blockDim.x + threadIdx.x;
    if (i < n4) {
        float4 v = ((const float4*)in)[i];
        ushort4 o;
        o.x = f2bf(v.x); o.y = f2bf(v.y); o.z = f2bf(v.z); o.w = f2bf(v.w);
        ((ushort4*)outh)[i] = o;
    }
}

// ---------- K1: count in-degrees (int atomics, 640K ops) ----------
__global__ void k_count(const int* __restrict__ dst, int* __restrict__ cnt, int E) {
    int e = blockIdx.x * blockDim.x + threadIdx.x;
    if (e < E) atomicAdd(&cnt[dst[e]], 1);
}

// ---------- K2a: per-1024-chunk sums ----------
__global__ void k_bsum(const int* __restrict__ cnt, int* __restrict__ bsum, int V) {
    __shared__ int red[4];
    int b = blockIdx.x, t = threadIdx.x;
    int s = 0;
    int base = b * 1024;
    for (int i = 0; i < 4; ++i) {
        int idx = base + i * 256 + t;
        if (idx < V) s += cnt[idx];
    }
    for (int m = 32; m >= 1; m >>= 1) s += __shfl_xor(s, m, 64);
    int lane = t & 63, wid = t >> 6;
    if (lane == 0) red[wid] = s;
    __syncthreads();
    if (t == 0) bsum[b] = red[0] + red[1] + red[2] + red[3];
}

// ---------- K2b: tiny serial scan of chunk sums ----------
__global__ void k_bscan(const int* __restrict__ bsum, int* __restrict__ boff, int nb) {
    if (threadIdx.x == 0 && blockIdx.x == 0) {
        int run = 0;
        for (int i = 0; i < nb; ++i) { boff[i] = run; run += bsum[i]; }
    }
}

// ---------- K2c: exclusive CSR offsets + dinv = 1/sqrt(deg+1) ----------
__global__ void k_offs(const int* __restrict__ cnt, const int* __restrict__ boff,
                       int* __restrict__ offs, float* __restrict__ dinv, int V) {
    __shared__ int wsum[4];
    int b = blockIdx.x, t = threadIdx.x;
    int lane = t & 63, wid = t >> 6;
    int base = b * 1024 + t * 4;
    int c[4];
    for (int j = 0; j < 4; ++j) {
        int idx = base + j;
        c[j] = (idx < V) ? cnt[idx] : 0;
    }
    int tot = c[0] + c[1] + c[2] + c[3];
    int x = tot;
    for (int off = 1; off < 64; off <<= 1) {
        int n = __shfl_up(x, off, 64);
        if (lane >= off) x += n;
    }
    int lex = x - tot;               // exclusive prefix within wave (of thread totals)
    if (lane == 63) wsum[wid] = x;   // wave total
    __syncthreads();
    int wpre = 0;
    for (int w = 0; w < wid; ++w) wpre += wsum[w];
    int o = boff[b] + wpre + lex;
    int pre = 0;
    for (int j = 0; j < 4; ++j) {
        int idx = base + j;
        if (idx < V) {
            offs[idx] = o + pre;
            dinv[idx] = 1.0f / sqrtf((float)(c[j] + 1));  // deg includes self-loop
        }
        pre += c[j];
    }
}

// ---------- K3: fill CSR (int atomic cursors) ----------
__global__ void k_fill(const int* __restrict__ src, const int* __restrict__ dst,
                       const int* __restrict__ offs, int* __restrict__ cursor,
                       int* __restrict__ csr, int E) {
    int e = blockIdx.x * blockDim.x + threadIdx.x;
    if (e < E) {
        int d = dst[e];
        int pos = atomicAdd(&cursor[d], 1);
        csr[offs[d] + pos] = src[e];
    }
}

// ---------- K4: aggregate in EMBEDDING space, bf16 gathers (halved miss count) ----------
// one wave per node; lane holds 2 dims (one packed bf16x2 = 4B).
__global__ __launch_bounds__(256) void k_agg(const unsigned short* __restrict__ emb_h,
                     const int* __restrict__ offs, const int* __restrict__ cnt,
                     const int* __restrict__ csr, const float* __restrict__ dinv,
                     float* __restrict__ out, int V) {
    int wid = threadIdx.x >> 6;
    int lane = threadIdx.x & 63;
    int v = blockIdx.x * 4 + wid;
    if (v >= V) return;
    float dv = dinv[v];
    int beg = offs[v], num = cnt[v];
    int nid = 0; float nw = 0.0f;
    if (lane < num) {                       // one coalesced id load + one dinv gather
        nid = csr[beg + lane];
        nw = dinv[nid];
    }
    unsigned u0 = ((const unsigned*)(emb_h + (size_t)v * DIM))[lane];
    float wself = dv * dv;                  // self-loop norm
    float2 acc;
    acc.x = wself * bl(u0); acc.y = wself * bh(u0);
    int n0 = min(num, 64);
    for (int i = 0; i < n0; ++i) {
        int s = __shfl(nid, i, 64);
        float w = dv * __shfl(nw, i, 64);
        unsigned u = ((const unsigned*)(emb_h + (size_t)s * DIM))[lane];
        acc.x += w * bl(u); acc.y += w * bh(u);
    }
    for (int i = 64; i < num; ++i) {        // cold fallback (deg>64 ~ impossible, Poisson(6.4))
        int s = csr[beg + i];
        float w = dv * dinv[s];
        unsigned u = ((const unsigned*)(emb_h + (size_t)s * DIM))[lane];
        acc.x += w * bl(u); acc.y += w * bh(u);
    }
    ((float2*)(out + (size_t)v * DIM))[lane] = acc;
}

// ---------- K5: in-place GEMM  nodes = nodes @ W + bias; also emit bf16 copy ----------
__global__ __launch_bounds__(256) void k_gemm(float* __restrict__ nodes,
                      unsigned short* __restrict__ nodes_h,
                      const float* __restrict__ W, const float* __restrict__ bias, int V) {
    __shared__ float rows[32][128];   // 16 KB
    __shared__ float wld[32][128];    // 16 KB
    int t = threadIdx.x;
    int rowbase = blockIdx.x * 32;
    {   // stage 32 rows (4096 floats) as float4
        const float4* g = (const float4*)(nodes + (size_t)rowbase * DIM);
        float4* s = (float4*)&rows[0][0];
        #pragma unroll
        for (int i = 0; i < 4; ++i) s[t + i * 256] = g[t + i * 256];
    }
    int tr = t >> 5, tc = t & 31;
    float acc[4][4] = {{0.f}};
    for (int kt = 0; kt < 4; ++kt) {
        __syncthreads();              // rows staged (kt=0) / wld reads done (kt>0)
        {   // stage W rows [kt*32, kt*32+32)
            const float4* g = (const float4*)(W + kt * 32 * DIM);
            float4* s = (float4*)&wld[0][0];
            #pragma unroll
            for (int i = 0; i < 4; ++i) s[t + i * 256] = g[t + i * 256];
        }
        __syncthreads();
        #pragma unroll
        for (int k = 0; k < 32; ++k) {
            float4 wv = *(const float4*)&wld[k][tc * 4];
            float a0 = rows[tr * 4 + 0][kt * 32 + k];
            float a1 = rows[tr * 4 + 1][kt * 32 + k];
            float a2 = rows[tr * 4 + 2][kt * 32 + k];
            float a3 = rows[tr * 4 + 3][kt * 32 + k];
            acc[0][0] += a0 * wv.x; acc[0][1] += a0 * wv.y; acc[0][2] += a0 * wv.z; acc[0][3] += a0 * wv.w;
            acc[1][0] += a1 * wv.x; acc[1][1] += a1 * wv.y; acc[1][2] += a1 * wv.z; acc[1][3] += a1 * wv.w;
            acc[2][0] += a2 * wv.x; acc[2][1] += a2 * wv.y; acc[2][2] += a2 * wv.z; acc[2][3] += a2 * wv.w;
            acc[3][0] += a3 * wv.x; acc[3][1] += a3 * wv.y; acc[3][2] += a3 * wv.z; acc[3][3] += a3 * wv.w;
        }
    }
    float4 bv = *(const float4*)&bias[tc * 4];
    #pragma unroll
    for (int i = 0; i < 4; ++i) {
        int r = rowbase + tr * 4 + i;
        if (r < V) {
            float4 o;
            o.x = acc[i][0] + bv.x; o.y = acc[i][1] + bv.y;
            o.z = acc[i][2] + bv.z; o.w = acc[i][3] + bv.w;
            *(float4*)(nodes + (size_t)r * DIM + tc * 4) = o;
            ushort4 oh;
            oh.x = f2bf(o.x); oh.y = f2bf(o.y); oh.z = f2bf(o.z); oh.w = f2bf(o.w);
            *(ushort4*)(nodes_h + (size_t)r * DIM + tc * 4) = oh;
        }
    }
}

// ---------- K6: scores[b,s] = dot(nodes[items[b]], nodes_h[samples[b,s]]) ----------
// one block per item; 4 threads per sample. Item row fp32 (L1-reused 64x),
// sample rows bf16 (256B/row -> half the L1 misses of fp32).
__global__ __launch_bounds__(256) void k_score(const float* __restrict__ nodes,
                      const unsigned short* __restrict__ nodes_h,
                      const int* __restrict__ items, const int* __restrict__ samples,
                      float* __restrict__ out) {
    int b = blockIdx.x;
    int t = threadIdx.x;
    int q = t & 3;       // dim-chunk 0..3 (32 floats each)
    int sidx = t >> 2;   // sample 0..63
    int item = items[b];
    const float4* irow = (const float4*)(nodes + (size_t)item * DIM + q * 32);
    float4 iv[8];
    #pragma unroll
    for (int i = 0; i < 8; ++i) iv[i] = irow[i];   // broadcast across 4 q-groups, L1-hit

    int j = samples[b * SAMP + sidx];
    const uint4* srow = (const uint4*)(nodes_h + (size_t)j * DIM + q * 32);
    uint4 sv[4];
    #pragma unroll
    for (int c = 0; c < 4; ++c) sv[c] = srow[c];   // 4 independent 16B loads in flight

    float p = 0.f;
    #pragma unroll
    for (int c = 0; c < 4; ++c) {
        float4 a0 = iv[c * 2 + 0], a1 = iv[c * 2 + 1];
        p += a0.x * bl(sv[c].x) + a0.y * bh(sv[c].x)
           + a0.z * bl(sv[c].y) + a0.w * bh(sv[c].y)
           + a1.x * bl(sv[c].z) + a1.y * bh(sv[c].z)
           + a1.z * bl(sv[c].w) + a1.w * bh(sv[c].w);
    }
    p += __shfl_xor(p, 1, 64);
    p += __shfl_xor(p, 2, 64);
    if (q == 0) out[b * SAMP + sidx] = p;
}

extern "C" void kernel_launch(void* const* d_in, const int* in_sizes, int n_in,
                              void* d_out, int out_size, void* d_ws, size_t ws_size,
                              hipStream_t stream) {
    const int*   items   = (const int*)d_in[0];
    const int*   samples = (const int*)d_in[1];
    const int*   edges   = (const int*)d_in[2];
    const float* emb     = (const float*)d_in[3];
    const float* W       = (const float*)d_in[4];
    const float* bias    = (const float*)d_in[5];
    float* out = (float*)d_out;

    char* ws = (char*)d_ws;
    int*   cnt    = (int*)(ws + 0);                    // V ints
    int*   cursor = (int*)(ws + (512 << 10));          // V ints
    float* dinv   = (float*)(ws + (1 << 20));          // V floats
    int*   offs   = (int*)(ws + 3 * (512 << 10));      // V ints
    int*   bsum   = (int*)(ws + (2 << 20));            // ~98 ints
    int*   boff   = (int*)(ws + (2 << 20) + 4096);     // ~98 ints
    int*   csr    = (int*)(ws + (4 << 20));            // E ints (2.56 MB)
    unsigned short* emb_h   = (unsigned short*)(ws + (8 << 20));   // V*DIM bf16 (25.6 MB)
    unsigned short* nodes_h = emb_h;                   // reuse: emb_h dead after k_agg
    float* nodes  = (float*)(ws + (34 << 20));         // V*DIM fp32 (51.2 MB, ends ~85.2 MB)

    const int* esrc = edges;
    const int* edst = edges + NEDGE;

    hipMemsetAsync(ws, 0, (1 << 20), stream);  // zero cnt + cursor

    int nb = (V_NODES + 1023) / 1024;
    int n4 = V_NODES * DIM / 4;
    k_cvt  <<<(n4 + 255) / 256, 256, 0, stream>>>(emb, emb_h, n4);
    k_count<<<(NEDGE + 255) / 256, 256, 0, stream>>>(edst, cnt, NEDGE);
    k_bsum <<<nb, 256, 0, stream>>>(cnt, bsum, V_NODES);
    k_bscan<<<1, 64, 0, stream>>>(bsum, boff, nb);
    k_offs <<<nb, 256, 0, stream>>>(cnt, boff, offs, dinv, V_NODES);
    k_fill <<<(NEDGE + 255) / 256, 256, 0, stream>>>(esrc, edst, offs, cursor, csr, NEDGE);
    k_agg  <<<(V_NODES + 3) / 4, 256, 0, stream>>>(emb_h, offs, cnt, csr, dinv, nodes, V_NODES);
    k_gemm <<<V_NODES / 32, 256, 0, stream>>>(nodes, nodes_h, W, bias, V_NODES);
    k_score<<<BATCH, 256, 0, stream>>>(nodes, nodes_h, items, samples, out);
}